// Round 3
// baseline (295.166 us; speedup 1.0000x reference)
//
#include <hip/hip_runtime.h>
#include <math.h>

// Problem constants
constexpr int Bc  = 32;
constexpr int Cc  = 1024;
constexpr int Mc  = 1024;
constexpr int Dc  = 512;
constexpr int DVc = 512;
constexpr int Rc  = 64;

typedef float f4 __attribute__((ext_vector_type(4)));

// ---------------------------------------------------------------------------
// Stage 1 of Ksum/Vsum, with Tsum fused in.
// Block = (c-chunk cs of 64, b). Phase 1: 64 row-sums of T[b, c0+r, :]
// (reads T once across the grid, coalesced float4). Phase 2: partial
// pK[b,cs,d] = sum_{c in chunk} Tsum[c] * Wk[c,d] (and pV with Wv).
// Grid (16, 32) = 512 blocks.
// ---------------------------------------------------------------------------
__global__ __launch_bounds__(256) void k_kv1(const float* __restrict__ T,
                                             const float* __restrict__ Wk,
                                             const float* __restrict__ Wv,
                                             float* __restrict__ pK,
                                             float* __restrict__ pV) {
    __shared__ float ts[64];
    const int cs  = blockIdx.x;
    const int b   = blockIdx.y;
    const int c0  = cs * 64;
    const int tid = threadIdx.x;
    const int w   = tid >> 6, lane = tid & 63;

    const float* Tb = T + ((long)b * Cc + c0) * Mc;
#pragma unroll 4
    for (int r = w * 16; r < w * 16 + 16; ++r) {
        const float* row = Tb + (long)r * Mc;
        float s = 0.f;
#pragma unroll
        for (int k = 0; k < 4; ++k) {
            float4 t = *(const float4*)&row[k * 256 + lane * 4];
            s += (t.x + t.y) + (t.z + t.w);
        }
#pragma unroll
        for (int off = 32; off; off >>= 1) s += __shfl_down(s, off, 64);
        if (lane == 0) ts[r] = s;
    }
    __syncthreads();

    const int d = tid;  // covers d and d+256
    float k1 = 0.f, k2 = 0.f, v1 = 0.f, v2 = 0.f;
#pragma unroll 4
    for (int c = 0; c < 64; ++c) {
        float t = ts[c];  // LDS broadcast
        const float* wkr = Wk + (long)(c0 + c) * Dc;
        const float* wvr = Wv + (long)(c0 + c) * DVc;
        k1 = fmaf(t, wkr[d],       k1);
        k2 = fmaf(t, wkr[d + 256], k2);
        v1 = fmaf(t, wvr[d],       v1);
        v2 = fmaf(t, wvr[d + 256], v2);
    }
    const long base = ((long)b * 16 + cs) * 512;
    pK[base + d] = k1;  pK[base + d + 256] = k2;
    pV[base + d] = v1;  pV[base + d + 256] = v2;
}

// ---------------------------------------------------------------------------
// Stage 2: Ksum/Vsum[b,d] = sum over 16 c-chunks (blocks 0..127), PLUS the
// R_full row-sums folded in (blocks 128..143: rsum[r] = sum_m R_full[r,m]).
// Grid 144 blocks.
// ---------------------------------------------------------------------------
__global__ __launch_bounds__(256) void k_kv2r(const float* __restrict__ pK,
                                              const float* __restrict__ pV,
                                              float* __restrict__ Ksum,
                                              float* __restrict__ Vsum,
                                              const float* __restrict__ Rfull,
                                              float* __restrict__ rsum) {
    if (blockIdx.x < 128) {
        const int gid = blockIdx.x * 256 + threadIdx.x;  // 0..32767
        const int sel = gid >> 14;
        const int rem = gid & 16383;  // b*512 + d
        const float* p = (sel ? pV : pK) + (long)(rem >> 9) * 16 * 512 + (rem & 511);
        float s = 0.f;
#pragma unroll
        for (int i = 0; i < 16; ++i) s += p[i * 512];
        (sel ? Vsum : Ksum)[rem] = s;
    } else {
        const int row  = (blockIdx.x - 128) * 4 + (threadIdx.x >> 6);  // 0..63
        const int lane = threadIdx.x & 63;
        const float* xr = Rfull + (long)row * 1024;
        float s = 0.f;
#pragma unroll
        for (int k = 0; k < 4; ++k) {
            float4 t = *(const float4*)&xr[k * 256 + lane * 4];
            s += (t.x + t.y) + (t.z + t.w);
        }
#pragma unroll
        for (int off = 32; off; off >>= 1) s += __shfl_down(s, off, 64);
        if (lane == 0) rsum[row] = s;
    }
}

// ---------------------------------------------------------------------------
// Merged middle kernel (both parts depend only on Ksum/Vsum):
//  blocks [0, 8192):    wqk[b,c] = sum_d Wq[c,d]*Ksum[b,d]  (wave per (b,c))
//  blocks [8192, 8448): vw stage 1 — pVW[b,ds,c] partials over 64-d chunks
// ---------------------------------------------------------------------------
__global__ __launch_bounds__(256) void k_mid(const float* __restrict__ Wq,
                                             const float* __restrict__ Ksum,
                                             float* __restrict__ wqk,
                                             const float* __restrict__ Wout,
                                             const float* __restrict__ Vsum,
                                             float* __restrict__ pVW) {
    __shared__ float vs[64];
    if (blockIdx.x < 8192) {
        const int wid  = blockIdx.x * 4 + (threadIdx.x >> 6);  // b*1024 + c
        const int lane = threadIdx.x & 63;
        const float* wq = Wq + (long)(wid & 1023) * Dc;
        const float* ks = Ksum + (wid >> 10) * Dc;
        float s = 0.f;
#pragma unroll
        for (int k = 0; k < 4; ++k) {
            int d = k * 128 + lane * 2;
            float2 a = *(const float2*)&wq[d];
            float2 x = *(const float2*)&ks[d];
            s = fmaf(a.x, x.x, s);
            s = fmaf(a.y, x.y, s);
        }
#pragma unroll
        for (int off = 32; off; off >>= 1) s += __shfl_down(s, off, 64);
        if (lane == 0) wqk[wid] = s;
    } else {
        const int idx = blockIdx.x - 8192;
        const int ds  = idx & 7;
        const int b   = idx >> 3;
        const int d0  = ds * 64;
        const int tid = threadIdx.x;
        if (tid < 64) vs[tid] = Vsum[b * Dc + d0 + tid];
        __syncthreads();
        float a0 = 0.f, a1 = 0.f, a2 = 0.f, a3 = 0.f;
        const float* W0 = Wout + (long)d0 * Cc + tid;
#pragma unroll 4
        for (int d = 0; d < 64; ++d) {
            float v = vs[d];
            const float* wr = W0 + (long)d * Cc;
            a0 = fmaf(v, wr[0],   a0);
            a1 = fmaf(v, wr[256], a1);
            a2 = fmaf(v, wr[512], a2);
            a3 = fmaf(v, wr[768], a3);
        }
        const long base = ((long)b * 8 + ds) * 1024 + tid;
        pVW[base] = a0;  pVW[base + 256] = a1;
        pVW[base + 512] = a2;  pVW[base + 768] = a3;
    }
}

// Stage 2 of vw: reduce the 8 partials. Grid 128 blocks.
__global__ __launch_bounds__(256) void k_vw2(const float* __restrict__ pVW,
                                             float* __restrict__ vw) {
    const int gid = blockIdx.x * 256 + threadIdx.x;  // b*1024 + c
    const float* p = pVW + (long)(gid >> 10) * 8 * 1024 + (gid & 1023);
    float s = 0.f;
#pragma unroll
    for (int i = 0; i < 8; ++i) s += p[i * 1024];
    vw[gid] = s;
}

// ---------------------------------------------------------------------------
// Fused final: per (b, 64-m tile):
//   qk[i]  = sum_c T[b,c,i] * wqk[b,c]
//   w[i]   = sum_r softmax_r(scale*qk[i]*rsum[r]) * rsum[r]
//   Out[b,c,i] = w[i] * vw[b,c]   (nontemporal store: keep T in L3)
// wqk/vw rows staged in LDS (halves vmem instruction count in both passes);
// unroll 8 on the accumulate pass for 8 T-loads in flight per thread.
// ---------------------------------------------------------------------------
__global__ __launch_bounds__(256) void k_final(const float* __restrict__ T,
                                               const float* __restrict__ wqk,
                                               const float* __restrict__ vw,
                                               const float* __restrict__ rsum,
                                               float* __restrict__ Out,
                                               float scale) {
    __shared__ float rs[64];
    __shared__ float part[16][72];
    __shared__ float wsh[64];
    __shared__ float wql[Cc];
    __shared__ float vwl[Cc];

    const int b  = blockIdx.y;
    const int m0 = blockIdx.x * 64;
    const int il = threadIdx.x & 15;
    const int cs = threadIdx.x >> 4;

    // stage wqk[b,:] and vw[b,:] (4 KB each) into LDS, coalesced float4
    ((float4*)wql)[threadIdx.x] = ((const float4*)(wqk + b * Cc))[threadIdx.x];
    ((float4*)vwl)[threadIdx.x] = ((const float4*)(vw + b * Cc))[threadIdx.x];
    if (threadIdx.x < 64) rs[threadIdx.x] = rsum[threadIdx.x];
    __syncthreads();

    const float* Tbm = T + (long)b * Cc * Mc + m0 + il * 4;

    float4 acc = make_float4(0.f, 0.f, 0.f, 0.f);
#pragma unroll 8
    for (int c = cs; c < Cc; c += 16) {
        float4 t = *(const float4*)&Tbm[(long)c * Mc];
        float wc = wql[c];  // LDS broadcast (2-way bank alias = free)
        acc.x = fmaf(t.x, wc, acc.x);
        acc.y = fmaf(t.y, wc, acc.y);
        acc.z = fmaf(t.z, wc, acc.z);
        acc.w = fmaf(t.w, wc, acc.w);
    }
    *(float4*)&part[cs][il * 4] = acc;
    __syncthreads();

    if (threadIdx.x < 64) {
        const int i = threadIdx.x;
        float q = 0.f;
#pragma unroll
        for (int k = 0; k < 16; ++k) q += part[k][i];
        q *= scale;
        float mx = -1e30f;
#pragma unroll
        for (int r = 0; r < 64; ++r) mx = fmaxf(mx, q * rs[r]);
        float se = 0.f, sw = 0.f;
#pragma unroll
        for (int r = 0; r < 64; ++r) {
            float e = __expf(q * rs[r] - mx);
            se += e;
            sw = fmaf(e, rs[r], sw);
        }
        wsh[i] = sw / se;
    }
    __syncthreads();

    float* Ob = Out + (long)b * Cc * Mc + m0 + il * 4;
    float4 w4 = *(const float4*)&wsh[il * 4];
#pragma unroll 4
    for (int c = cs; c < Cc; c += 16) {
        float v = vwl[c];
        f4 o = {w4.x * v, w4.y * v, w4.z * v, w4.w * v};
        __builtin_nontemporal_store(o, (f4*)&Ob[(long)c * Mc]);
    }
}

extern "C" void kernel_launch(void* const* d_in, const int* in_sizes, int n_in,
                              void* d_out, int out_size, void* d_ws, size_t ws_size,
                              hipStream_t stream) {
    const float* T     = (const float*)d_in[0];  // (B,C,M)
    const float* Wq    = (const float*)d_in[1];  // (C,D)
    const float* Wk    = (const float*)d_in[2];  // (C,D)
    const float* Wv    = (const float*)d_in[3];  // (C,DV)
    const float* Wout  = (const float*)d_in[4];  // (DV,C)
    const float* Rfull = (const float*)d_in[5];  // (R,M)
    float* Out = (float*)d_out;

    float* ws   = (float*)d_ws;
    float* rsum = ws;                  // 64
    float* Ksum = rsum + Rc;           // 16384
    float* Vsum = Ksum + Bc * Dc;      // 16384
    float* wqk  = Vsum + Bc * DVc;     // 32768
    float* vw   = wqk + Bc * Cc;       // 32768
    float* pK   = vw + Bc * Cc;        // 32*16*512 = 262144
    float* pV   = pK + 262144;         // 262144
    float* pVW  = pV + 262144;         // 32*8*1024 = 262144

    // 1) kv stage 1 (fused Tsum): reads all of T once
    k_kv1<<<dim3(16, Bc), 256, 0, stream>>>(T, Wk, Wv, pK, pV);
    // 2) kv stage 2 + rsum folded in
    k_kv2r<<<144, 256, 0, stream>>>(pK, pV, Ksum, Vsum, Rfull, rsum);
    // 3) merged wqk + vw stage 1
    k_mid<<<8448, 256, 0, stream>>>(Wq, Ksum, wqk, Wout, Vsum, pVW);
    // 4) vw stage 2
    k_vw2<<<128, 256, 0, stream>>>(pVW, vw);
    // 5) fused scores/softmax/output
    const float scale = 1.0f / sqrtf((float)Dc);
    k_final<<<dim3(Mc / 64, Bc), 256, 0, stream>>>(T, wqk, vw, rsum, Out, scale);
}

// Round 5
// 290.408 us; speedup vs baseline: 1.0164x; 1.0164x over previous
//
#include <hip/hip_runtime.h>
#include <math.h>

// Problem constants
constexpr int Bc  = 32;
constexpr int Cc  = 1024;
constexpr int Mc  = 1024;
constexpr int Dc  = 512;
constexpr int DVc = 512;
constexpr int Rc  = 64;

typedef float f4 __attribute__((ext_vector_type(4)));

// ---------------------------------------------------------------------------
// Stage 1 of Ksum/Vsum, with Tsum fused in. 512 threads (8 waves) per block
// for 16 waves/CU at 2 blocks/CU (was 8 waves/CU -> latency-bound suspicion).
// Phase 1: 8 waves x 8 rows = 64 row-sums of T[b, c0+r, :] (coalesced float4).
// Phase 2: partial pK[b,cs,d] = sum_{c in chunk} Tsum[c] * Wk[c,d] (and pV),
// d = tid covers all 512 d in one go. Grid (16, 32) = 512 blocks.
// ---------------------------------------------------------------------------
__global__ __launch_bounds__(512) void k_kv1(const float* __restrict__ T,
                                             const float* __restrict__ Wk,
                                             const float* __restrict__ Wv,
                                             float* __restrict__ pK,
                                             float* __restrict__ pV) {
    __shared__ float ts[64];
    const int cs  = blockIdx.x;
    const int b   = blockIdx.y;
    const int c0  = cs * 64;
    const int tid = threadIdx.x;
    const int w   = tid >> 6, lane = tid & 63;  // w = 0..7

    const float* Tb = T + ((long)b * Cc + c0) * Mc;
#pragma unroll 4
    for (int r = w * 8; r < w * 8 + 8; ++r) {
        const float* row = Tb + (long)r * Mc;
        float s = 0.f;
#pragma unroll
        for (int k = 0; k < 4; ++k) {
            float4 t = *(const float4*)&row[k * 256 + lane * 4];
            s += (t.x + t.y) + (t.z + t.w);
        }
#pragma unroll
        for (int off = 32; off; off >>= 1) s += __shfl_down(s, off, 64);
        if (lane == 0) ts[r] = s;
    }
    __syncthreads();

    const int d = tid;  // 0..511 covers all of D
    float k1 = 0.f, v1 = 0.f;
#pragma unroll 4
    for (int c = 0; c < 64; ++c) {
        float t = ts[c];  // LDS broadcast
        k1 = fmaf(t, Wk[(long)(c0 + c) * Dc  + d], k1);
        v1 = fmaf(t, Wv[(long)(c0 + c) * DVc + d], v1);
    }
    const long base = ((long)b * 16 + cs) * 512;
    pK[base + d] = k1;
    pV[base + d] = v1;
}

// ---------------------------------------------------------------------------
// Stage 2: Ksum/Vsum[b,d] = sum over 16 c-chunks (blocks 0..127), PLUS the
// R_full row-sums folded in (blocks 128..143: rsum[r] = sum_m R_full[r,m]).
// Grid 144 blocks.
// ---------------------------------------------------------------------------
__global__ __launch_bounds__(256) void k_kv2r(const float* __restrict__ pK,
                                              const float* __restrict__ pV,
                                              float* __restrict__ Ksum,
                                              float* __restrict__ Vsum,
                                              const float* __restrict__ Rfull,
                                              float* __restrict__ rsum) {
    if (blockIdx.x < 128) {
        const int gid = blockIdx.x * 256 + threadIdx.x;  // 0..32767
        const int sel = gid >> 14;
        const int rem = gid & 16383;  // b*512 + d
        const float* p = (sel ? pV : pK) + (long)(rem >> 9) * 16 * 512 + (rem & 511);
        float s = 0.f;
#pragma unroll
        for (int i = 0; i < 16; ++i) s += p[i * 512];
        (sel ? Vsum : Ksum)[rem] = s;
    } else {
        const int row  = (blockIdx.x - 128) * 4 + (threadIdx.x >> 6);  // 0..63
        const int lane = threadIdx.x & 63;
        const float* xr = Rfull + (long)row * 1024;
        float s = 0.f;
#pragma unroll
        for (int k = 0; k < 4; ++k) {
            float4 t = *(const float4*)&xr[k * 256 + lane * 4];
            s += (t.x + t.y) + (t.z + t.w);
        }
#pragma unroll
        for (int off = 32; off; off >>= 1) s += __shfl_down(s, off, 64);
        if (lane == 0) rsum[row] = s;
    }
}

// ---------------------------------------------------------------------------
// Merged middle kernel (both parts depend only on Ksum/Vsum):
//  blocks [0, 8192):    wqk[b,c] = sum_d Wq[c,d]*Ksum[b,d]  (wave per (b,c))
//  blocks [8192, 8448): vw stage 1 — pVW[b,ds,c] partials over 64-d chunks
// ---------------------------------------------------------------------------
__global__ __launch_bounds__(256) void k_mid(const float* __restrict__ Wq,
                                             const float* __restrict__ Ksum,
                                             float* __restrict__ wqk,
                                             const float* __restrict__ Wout,
                                             const float* __restrict__ Vsum,
                                             float* __restrict__ pVW) {
    __shared__ float vs[64];
    if (blockIdx.x < 8192) {
        const int wid  = blockIdx.x * 4 + (threadIdx.x >> 6);  // b*1024 + c
        const int lane = threadIdx.x & 63;
        const float* wq = Wq + (long)(wid & 1023) * Dc;
        const float* ks = Ksum + (wid >> 10) * Dc;
        float s = 0.f;
#pragma unroll
        for (int k = 0; k < 4; ++k) {
            int d = k * 128 + lane * 2;
            float2 a = *(const float2*)&wq[d];
            float2 x = *(const float2*)&ks[d];
            s = fmaf(a.x, x.x, s);
            s = fmaf(a.y, x.y, s);
        }
#pragma unroll
        for (int off = 32; off; off >>= 1) s += __shfl_down(s, off, 64);
        if (lane == 0) wqk[wid] = s;
    } else {
        const int idx = blockIdx.x - 8192;
        const int ds  = idx & 7;
        const int b   = idx >> 3;
        const int d0  = ds * 64;
        const int tid = threadIdx.x;
        if (tid < 64) vs[tid] = Vsum[b * Dc + d0 + tid];
        __syncthreads();
        float a0 = 0.f, a1 = 0.f, a2 = 0.f, a3 = 0.f;
        const float* W0 = Wout + (long)d0 * Cc + tid;
#pragma unroll 4
        for (int d = 0; d < 64; ++d) {
            float v = vs[d];
            const float* wr = W0 + (long)d * Cc;
            a0 = fmaf(v, wr[0],   a0);
            a1 = fmaf(v, wr[256], a1);
            a2 = fmaf(v, wr[512], a2);
            a3 = fmaf(v, wr[768], a3);
        }
        const long base = ((long)b * 8 + ds) * 1024 + tid;
        pVW[base] = a0;  pVW[base + 256] = a1;
        pVW[base + 512] = a2;  pVW[base + 768] = a3;
    }
}

// ---------------------------------------------------------------------------
// Fused final, 512 threads (16 waves/CU at 2 blocks/CU). Per (b, 64-m tile):
//   vwl[c] = sum_8 pVW partials  (vw stage-2 folded in; L2-resident reads)
//   qk[i]  = sum_c T[b,c,i] * wqk[b,c]     (32 c-slices/thread, was 64)
//   w[i]   = sum_r softmax_r(scale*qk[i]*rsum[r]) * rsum[r]
//   Out[b,c,i] = w[i] * vwl[c]             (nontemporal stores)
// ---------------------------------------------------------------------------
__global__ __launch_bounds__(512) void k_final(const float* __restrict__ T,
                                               const float* __restrict__ wqk,
                                               const float* __restrict__ pVW,
                                               const float* __restrict__ rsum,
                                               float* __restrict__ Out,
                                               float scale) {
    __shared__ float rs[64];
    __shared__ float part[32][72];
    __shared__ float wsh[64];
    __shared__ float wql[Cc];
    __shared__ float vwl[Cc];

    const int b   = blockIdx.y;
    const int m0  = blockIdx.x * 64;
    const int tid = threadIdx.x;
    const int il  = tid & 15;
    const int cs  = tid >> 4;  // 0..31

    // stage wqk[b,:] (float4 by first 256 threads)
    if (tid < 256) ((float4*)wql)[tid] = ((const float4*)(wqk + b * Cc))[tid];
    // vw stage 2 folded: vwl[c] = sum_{j<8} pVW[b,j,c]  (2 c per thread)
#pragma unroll
    for (int c = tid; c < Cc; c += 512) {
        const float* p = pVW + (long)b * 8 * 1024 + c;
        float s = 0.f;
#pragma unroll
        for (int j = 0; j < 8; ++j) s += p[j * 1024];
        vwl[c] = s;
    }
    if (tid < 64) rs[tid] = rsum[tid];
    __syncthreads();

    const float* Tbm = T + (long)b * Cc * Mc + m0 + il * 4;

    float4 acc = make_float4(0.f, 0.f, 0.f, 0.f);
#pragma unroll 8
    for (int c = cs; c < Cc; c += 32) {
        float4 t = *(const float4*)&Tbm[(long)c * Mc];
        float wc = wql[c];  // LDS broadcast
        acc.x = fmaf(t.x, wc, acc.x);
        acc.y = fmaf(t.y, wc, acc.y);
        acc.z = fmaf(t.z, wc, acc.z);
        acc.w = fmaf(t.w, wc, acc.w);
    }
    *(float4*)&part[cs][il * 4] = acc;
    __syncthreads();

    if (tid < 64) {
        const int i = tid;
        float q = 0.f;
#pragma unroll
        for (int k = 0; k < 32; ++k) q += part[k][i];
        q *= scale;
        float mx = -1e30f;
#pragma unroll
        for (int r = 0; r < 64; ++r) mx = fmaxf(mx, q * rs[r]);
        float se = 0.f, sw = 0.f;
#pragma unroll
        for (int r = 0; r < 64; ++r) {
            float e = __expf(q * rs[r] - mx);
            se += e;
            sw = fmaf(e, rs[r], sw);
        }
        wsh[i] = sw / se;
    }
    __syncthreads();

    float* Ob = Out + (long)b * Cc * Mc + m0 + il * 4;
    float4 w4 = *(const float4*)&wsh[il * 4];
#pragma unroll 4
    for (int c = cs; c < Cc; c += 32) {
        float v = vwl[c];
        f4 o = {w4.x * v, w4.y * v, w4.z * v, w4.w * v};
        __builtin_nontemporal_store(o, (f4*)&Ob[(long)c * Mc]);
    }
}

extern "C" void kernel_launch(void* const* d_in, const int* in_sizes, int n_in,
                              void* d_out, int out_size, void* d_ws, size_t ws_size,
                              hipStream_t stream) {
    const float* T     = (const float*)d_in[0];  // (B,C,M)
    const float* Wq    = (const float*)d_in[1];  // (C,D)
    const float* Wk    = (const float*)d_in[2];  // (C,D)
    const float* Wv    = (const float*)d_in[3];  // (C,DV)
    const float* Wout  = (const float*)d_in[4];  // (DV,C)
    const float* Rfull = (const float*)d_in[5];  // (R,M)
    float* Out = (float*)d_out;

    float* ws   = (float*)d_ws;
    float* rsum = ws;                  // 64
    float* Ksum = rsum + Rc;           // 16384
    float* Vsum = Ksum + Bc * Dc;      // 16384
    float* wqk  = Vsum + Bc * DVc;     // 32768
    float* vw   = wqk + Bc * Cc;       // 32768 (unused now, layout kept)
    float* pK   = vw + Bc * Cc;        // 32*16*512 = 262144
    float* pV   = pK + 262144;         // 262144
    float* pVW  = pV + 262144;         // 32*8*1024 = 262144

    // 1) kv stage 1 (fused Tsum): reads all of T once. 512-thread blocks.
    k_kv1<<<dim3(16, Bc), 512, 0, stream>>>(T, Wk, Wv, pK, pV);
    // 2) kv stage 2 + rsum folded in
    k_kv2r<<<144, 256, 0, stream>>>(pK, pV, Ksum, Vsum, Rfull, rsum);
    // 3) merged wqk + vw stage 1
    k_mid<<<8448, 256, 0, stream>>>(Wq, Ksum, wqk, Wout, Vsum, pVW);
    // 4) fused scores/softmax/output (vw stage 2 folded in). 512-thread blocks.
    const float scale = 1.0f / sqrtf((float)Dc);
    k_final<<<dim3(Mc / 64, Bc), 512, 0, stream>>>(T, wqk, pVW, rsum, Out, scale);
}